// Round 2
// baseline (547.174 us; speedup 1.0000x reference)
//
#include <hip/hip_runtime.h>

#define B_ 16
#define D_ 768
#define N_ 4096
#define Q_ 128

typedef __attribute__((ext_vector_type(4))) float f32x4;
typedef __attribute__((ext_vector_type(8))) short short8;
typedef __attribute__((ext_vector_type(4))) short sv4;

__device__ __forceinline__ unsigned short f2bf(float f) {
  union { float f; unsigned u; } x; x.f = f;
  unsigned u = x.u;
  unsigned r = u + 0x7fffu + ((u >> 16) & 1u);
  return (unsigned short)(r >> 16);
}
__device__ __forceinline__ float bf2f(unsigned short h) {
  union { unsigned u; float f; } x; x.u = ((unsigned)h) << 16;
  return x.f;
}

// ---------------- weight prep: z=0 cast Wv, z=1 transpose Wq, z=2 transpose Wk ------
__global__ __launch_bounds__(256) void weights_prep_kernel(
    const float* __restrict__ Wv, const float* __restrict__ Wq,
    const float* __restrict__ Wk,
    unsigned short* __restrict__ Wvb, unsigned short* __restrict__ WqTb,
    unsigned short* __restrict__ WkTb) {
  __shared__ float tile[32][33];
  const int z = blockIdx.z;
  if (z == 0) {
    int i = (blockIdx.y * 24 + blockIdx.x) * 256 + threadIdx.x;  // 576*256 = 768*768/4
    float4 v = ((const float4*)Wv)[i];
    ushort4 o;
    o.x = f2bf(v.x); o.y = f2bf(v.y); o.z = f2bf(v.z); o.w = f2bf(v.w);
    ((ushort4*)Wvb)[i] = o;
  } else {
    const float* src = (z == 1) ? Wq : Wk;
    unsigned short* dst = (z == 1) ? WqTb : WkTb;
    int bx = blockIdx.x * 32, by = blockIdx.y * 32;
    int tx = threadIdx.x & 31, ty = threadIdx.x >> 5;
    #pragma unroll
    for (int i = 0; i < 32; i += 8)
      tile[ty + i][tx] = src[(size_t)(by + ty + i) * D_ + bx + tx];
    __syncthreads();
    #pragma unroll
    for (int i = 0; i < 32; i += 8)
      dst[(size_t)(bx + ty + i) * D_ + by + tx] = f2bf(tile[tx][ty + i]);
  }
}

// ---------------- vec x mat: y=0 wkbq[d]=sum_n Wk[n,d]bq[n]; y=1 bias2[n]=sum_k bk[k]Wq[k,n];
// y=2 (x=0 only): bqbk = dot(bq,bk)
__global__ __launch_bounds__(256) void vecmat_kernel(
    const float* __restrict__ Wk, const float* __restrict__ Wq,
    const float* __restrict__ bq, const float* __restrict__ bk,
    float* __restrict__ wkbq, float* __restrict__ bias2, float* __restrict__ bqbk) {
  const int y = blockIdx.y, t = threadIdx.x;
  if (y == 2) {
    if (blockIdx.x != 0) return;
    float s = 0.f;
    for (int k = t; k < D_; k += 256) s += bq[k] * bk[k];
    #pragma unroll
    for (int off = 32; off; off >>= 1) s += __shfl_xor(s, off);
    __shared__ float red[4];
    if ((t & 63) == 0) red[t >> 6] = s;
    __syncthreads();
    if (t == 0) bqbk[0] = red[0] + red[1] + red[2] + red[3];
    return;
  }
  const float* M = y ? Wq : Wk;
  const float* vec = y ? bk : bq;
  float* outp = y ? bias2 : wkbq;
  const int col = blockIdx.x * 256 + t;
  float s = 0.f;
  #pragma unroll 4
  for (int n = 0; n < D_; n++) s += M[(size_t)n * D_ + col] * vec[n];
  outp[col] = s;
}

// ---------------- fused text prep: cast fp32->bf16, row entropy, AND skq row-dot ----
__global__ __launch_bounds__(256) void text_prep_kernel(
    const float* __restrict__ text, unsigned short* __restrict__ textb,
    float* __restrict__ ent, const float* __restrict__ wkbq,
    const float* __restrict__ bqbk, float* __restrict__ skq) {
  int row = blockIdx.x * 4 + (threadIdx.x >> 6);
  int lane = threadIdx.x & 63;
  const float4* src = (const float4*)(text + (size_t)row * D_);
  const float4* w4p = (const float4*)wkbq;
  ushort4* dst = (ushort4*)(textb + (size_t)row * D_);
  float s = 0.f, tt = 0.f, s2 = 0.f;
  #pragma unroll
  for (int j = 0; j < 3; j++) {
    float4 v = src[lane + 64 * j];
    float4 w = w4p[lane + 64 * j];
    float e0 = __expf(v.x), e1 = __expf(v.y), e2 = __expf(v.z), e3 = __expf(v.w);
    s += (e0 + e1) + (e2 + e3);
    tt += v.x * e0 + v.y * e1;
    tt += v.z * e2 + v.w * e3;
    s2 += v.x * w.x + v.y * w.y + v.z * w.z + v.w * w.w;
    ushort4 o;
    o.x = f2bf(v.x); o.y = f2bf(v.y); o.z = f2bf(v.z); o.w = f2bf(v.w);
    dst[lane + 64 * j] = o;
  }
  #pragma unroll
  for (int off = 32; off; off >>= 1) {
    s += __shfl_xor(s, off);
    tt += __shfl_xor(tt, off);
    s2 += __shfl_xor(s2, off);
  }
  if (lane == 0) {
    ent[row] = __logf(s) - tt / s;  // == m + log(sum e^{x-m}) - E_p[x]
    skq[row] = s2 + bqbk[0];
  }
}

// ---------------- softmax over 128 (te), one block/batch ----------------
__global__ __launch_bounds__(128) void softmax128_kernel(
    const float* __restrict__ ent, float* __restrict__ w) {
  int b = blockIdx.x, t = threadIdx.x;
  float v = ent[b * 128 + t];
  float m = v;
  #pragma unroll
  for (int off = 32; off; off >>= 1) m = fmaxf(m, __shfl_xor(m, off));
  __shared__ float sm2[2], ssum[2];
  int wv = t >> 6;
  if ((t & 63) == 0) sm2[wv] = m;
  __syncthreads();
  m = fmaxf(sm2[0], sm2[1]);
  float e = __expf(v - m);
  float s = e;
  #pragma unroll
  for (int off = 32; off; off >>= 1) s += __shfl_xor(s, off);
  if ((t & 63) == 0) ssum[wv] = s;
  __syncthreads();
  s = ssum[0] + ssum[1];
  w[b * 128 + t] = e / s;
}

// ---------------- softmax over 4096 (ve), one block/batch, 1024 thr ----------------
__global__ __launch_bounds__(1024) void softmax4096_kernel(
    const float* __restrict__ ent, float* __restrict__ w) {
  int b = blockIdx.x, t = threadIdx.x;
  const float* e = ent + (size_t)b * N_;
  float v[4];
  float m = -__builtin_inff();
  #pragma unroll
  for (int i = 0; i < 4; i++) { v[i] = e[t + 1024 * i]; m = fmaxf(m, v[i]); }
  #pragma unroll
  for (int off = 32; off; off >>= 1) m = fmaxf(m, __shfl_xor(m, off));
  __shared__ float red[16];
  int wv = t >> 6;
  if ((t & 63) == 0) red[wv] = m;
  __syncthreads();
  if (t < 16) {
    float x = red[t];
    #pragma unroll
    for (int off = 8; off; off >>= 1) x = fmaxf(x, __shfl_xor(x, off));
    red[t] = x;
  }
  __syncthreads();
  m = red[0];
  float ev[4];
  float s = 0.f;
  #pragma unroll
  for (int i = 0; i < 4; i++) { ev[i] = __expf(v[i] - m); s += ev[i]; }
  #pragma unroll
  for (int off = 32; off; off >>= 1) s += __shfl_xor(s, off);
  __syncthreads();
  if ((t & 63) == 0) red[wv] = s;
  __syncthreads();
  if (t < 16) {
    float x = red[t];
    #pragma unroll
    for (int off = 8; off; off >>= 1) x += __shfl_xor(x, off);
    red[t] = x;
  }
  __syncthreads();
  s = red[0];
  #pragma unroll
  for (int i = 0; i < 4; i++) w[(size_t)b * N_ + t + 1024 * i] = ev[i] / s;
}

// ---------------- visual entropy (FALLBACK path only) ----------------
__global__ __launch_bounds__(256) void visual_entropy_kernel(
    const float* __restrict__ vis, float* __restrict__ ent) {
  int bb = blockIdx.x >> 6;
  int n0 = (blockIdx.x & 63) * 64;
  int t = threadIdx.x;
  int tok = t & 63;
  int slice = t >> 6;
  const float* base = vis + (size_t)bb * D_ * N_ + (size_t)slice * 192 * N_ + n0 + tok;
  float m = -__builtin_inff(), s = 0.f, tt = 0.f;
  for (int d = 0; d < 192; d++) {
    float v = base[(size_t)d * N_];
    float nm = fmaxf(m, v);
    float c = __expf(m - nm);
    float e = __expf(v - nm);
    s = s * c + e; tt = tt * c + v * e; m = nm;
  }
  __shared__ float sm[256], ss[256], st[256];
  sm[t] = m; ss[t] = s; st[t] = tt;
  __syncthreads();
  if (t < 64) {
    #pragma unroll
    for (int k = 1; k < 4; k++) {
      float m2 = sm[t + 64 * k], s2 = ss[t + 64 * k], t2 = st[t + 64 * k];
      float nm = fmaxf(m, m2);
      float c1 = __expf(m - nm), c2 = __expf(m2 - nm);
      s = s * c1 + s2 * c2; tt = tt * c1 + t2 * c2; m = nm;
    }
    ent[(size_t)bb * N_ + n0 + t] = m + __logf(s) - tt / s;
  }
}

// ---------------- vis_prep: stream vis fp32 once -> visb bf16 [B][N][D] + entropy ---
__global__ __launch_bounds__(256) void vis_prep_kernel(
    const float* __restrict__ vis, unsigned short* __restrict__ visb,
    float* __restrict__ ent) {
  constexpr int LA = 68;
  __shared__ unsigned short As[128 * LA];   // 17408 B transpose tile
  __shared__ float2 esh[256];
  const int bb = blockIdx.x >> 5;
  const int n0 = (blockIdx.x & 31) * 128;
  const int t = threadIdx.x;
  const int smi = t & 127;
  const int ph = t >> 7;
  const float* abase = vis + (size_t)bb * D_ * N_ + n0;
  unsigned short* obase = visb + ((size_t)bb * N_ + n0) * D_;
  float es = 0.f, ets = 0.f;
  for (int k0 = 0; k0 < D_; k0 += 64) {
    __syncthreads();  // prior dump reads done before As overwrite
    #pragma unroll
    for (int i = 0; i < 16; i++) {
      const int kk = 2 * (ph + 2 * i);
      const float v0 = abase[(size_t)(k0 + kk) * N_ + smi];
      const float v1 = abase[(size_t)(k0 + kk + 1) * N_ + smi];
      const float e0 = __expf(v0), e1 = __expf(v1);
      es += e0 + e1;
      ets += v0 * e0 + v1 * e1;
      const unsigned pk = (unsigned)f2bf(v0) | ((unsigned)f2bf(v1) << 16);
      *(unsigned*)(As + smi * LA + kk) = pk;
    }
    __syncthreads();  // tile complete
    // dump tile rows: 128 rows x 64 shorts, uint2 (8B) stores
    #pragma unroll
    for (int i = 0; i < 8; i++) {
      const int c = t + 256 * i;
      const int n = c >> 4, m = c & 15;
      *(uint2*)(obase + (size_t)n * D_ + k0 + m * 4) = *(const uint2*)(As + n * LA + m * 4);
    }
  }
  esh[t] = {es, ets};
  __syncthreads();
  if (t < 128) {
    const float S = es + esh[t + 128].x;
    const float T = ets + esh[t + 128].y;
    ent[(size_t)bb * N_ + n0 + t] = __logf(S) - T / S;
  }
}

// ---------------- bf16 NT GEMM (BK=64): C[m,n] = sum_k A[m,k]*B[n,k] (+bias) --------
// MODE 0: store bf16 [M][768]; MODE 1: +bias; MODE 2: +bias, store vT[b][n][q]
template <int MODE>
__global__ __launch_bounds__(256) void gemm_nt_kernel(
    const unsigned short* __restrict__ A, const unsigned short* __restrict__ Bm,
    const float* __restrict__ bias, unsigned short* __restrict__ C) {
  constexpr int LDA = 72;
  __shared__ unsigned short As[64 * LDA];
  __shared__ unsigned short Bs[64 * LDA];
  int m0 = blockIdx.x * 64, n0 = blockIdx.y * 64;
  int t = threadIdx.x, wave = t >> 6, lane = t & 63;
  int wm = (wave & 1) * 32, wn = (wave >> 1) * 32;
  int fl = lane & 15, fq = lane >> 4;
  f32x4 acc[2][2];
  #pragma unroll
  for (int i = 0; i < 2; i++)
    #pragma unroll
    for (int j = 0; j < 2; j++) acc[i][j] = {0.f, 0.f, 0.f, 0.f};
  for (int k0 = 0; k0 < D_; k0 += 64) {
    __syncthreads();
    #pragma unroll
    for (int i = 0; i < 2; i++) {
      int c = t + 256 * i;
      int sr = c >> 3, sc = (c & 7) * 8;
      *(uint4*)(As + sr * LDA + sc) = *(const uint4*)(A + (size_t)(m0 + sr) * D_ + k0 + sc);
      *(uint4*)(Bs + sr * LDA + sc) = *(const uint4*)(Bm + (size_t)(n0 + sr) * D_ + k0 + sc);
    }
    __syncthreads();
    #pragma unroll
    for (int ks = 0; ks < 2; ks++) {
      short8 afr[2], bfr[2];
      #pragma unroll
      for (int i = 0; i < 2; i++)
        afr[i] = *(const short8*)(As + (wm + i * 16 + fl) * LDA + ks * 32 + fq * 8);
      #pragma unroll
      for (int j = 0; j < 2; j++)
        bfr[j] = *(const short8*)(Bs + (wn + j * 16 + fl) * LDA + ks * 32 + fq * 8);
      #pragma unroll
      for (int i = 0; i < 2; i++)
        #pragma unroll
        for (int j = 0; j < 2; j++)
          acc[i][j] = __builtin_amdgcn_mfma_f32_16x16x32_bf16(afr[i], bfr[j], acc[i][j], 0, 0, 0);
    }
  }
  #pragma unroll
  for (int i = 0; i < 2; i++)
    #pragma unroll
    for (int j = 0; j < 2; j++) {
      int n = n0 + wn + j * 16 + fl;
      float bb = (MODE >= 1) ? bias[n] : 0.f;
      #pragma unroll
      for (int r = 0; r < 4; r++) {
        int m = m0 + wm + i * 16 + fq * 4 + r;
        float val = acc[i][j][r] + bb;
        if (MODE == 2) {
          int bt = m >> 7, q = m & 127;
          C[((size_t)bt * D_ + n) * Q_ + q] = f2bf(val);
        } else {
          C[(size_t)m * D_ + n] = f2bf(val);
        }
      }
    }
}

// ---------------- fused attention main kernel ----------------
// per block: 128 tokens x full Q=128. S = vf*kq^T, softmax w/ ve*te modulation, O^T = vT*P^T
// ASRC=1: A staged from bf16 visb [B][N][D]; ASRC=0: A transposed+cast from fp32 vis.
template <int ASRC>
__global__ __launch_bounds__(256, 2) void attn_main_kernel(
    const float* __restrict__ vis,
    const unsigned short* __restrict__ visb,
    const unsigned short* __restrict__ kq,   // [B][Q][768] bf16
    const unsigned short* __restrict__ vT,   // [B][768][Q] bf16
    const float* __restrict__ ve,            // [B][4096]
    const float* __restrict__ te,            // [B][128]
    const float* __restrict__ skq,           // [B*Q]
    float* __restrict__ out)                 // [B][768][4096]
{
  constexpr int LA = 68;   // vf tile stride (bf16)
  constexpr int LB = 72;   // kq tile stride: 144B rows -> 16B-aligned b128 frags
  constexpr int LP = 136;  // P and V strides
  __shared__ unsigned short region0[30464];       // 60928 B
  __shared__ float stats[2][128][2];
  unsigned short* As = region0;                   // bytes [0, 17408)
  unsigned short* Bs = region0 + 8704;            // bytes [17408, 35840)
  unsigned short* Ps = region0;                   // bytes [0, 34816)   (A/B dead)
  unsigned short* Vs = region0 + 17408;           // bytes [34816, 60928)

  const int bb = blockIdx.x >> 5;
  const int n0 = (blockIdx.x & 31) * 128;
  const int t = threadIdx.x;
  const int wave = t >> 6, lane = t & 63;
  const int fl = lane & 15, fq = lane >> 4;
  const int wm = (wave & 1) * 64;   // token half (phase A)
  const int wq = (wave >> 1) * 64;  // q half (phase A)

  const float* abase = vis + (size_t)bb * D_ * N_ + n0;
  const unsigned short* vbrow = visb + ((size_t)bb * N_ + n0) * D_;
  const unsigned short* bbase = kq + (size_t)bb * Q_ * D_;

  f32x4 acc[4][4];
  #pragma unroll
  for (int i = 0; i < 4; i++)
    #pragma unroll
    for (int j = 0; j < 4; j++) acc[i][j] = {0.f, 0.f, 0.f, 0.f};

  const int smi = t & 127;
  const int ph = t >> 7;

  // ---------- phase A: S = vf * kq^T ----------
  for (int k0 = 0; k0 < D_; k0 += 64) {
    __syncthreads();
    if (ASRC == 1) {
      // stage A from bf16 rows: 128 rows x 64 shorts, uint4 load + 2x uint2 LDS write
      #pragma unroll
      for (int i = 0; i < 4; i++) {
        const int c = t + 256 * i;
        const int n = c >> 3, j = c & 7;
        const uint4 v = *(const uint4*)(vbrow + (size_t)n * D_ + k0 + j * 8);
        *(uint2*)(As + n * LA + j * 8) = {v.x, v.y};
        *(uint2*)(As + n * LA + j * 8 + 4) = {v.z, v.w};
      }
    } else {
      // stage A: transpose fp32 [k][n] -> bf16 [m][k], paired writes
      #pragma unroll
      for (int i = 0; i < 16; i++) {
        const int kk = 2 * (ph + 2 * i);
        const float v0 = abase[(size_t)(k0 + kk) * N_ + smi];
        const float v1 = abase[(size_t)(k0 + kk + 1) * N_ + smi];
        const unsigned pk = (unsigned)f2bf(v0) | ((unsigned)f2bf(v1) << 16);
        *(unsigned*)(As + smi * LA + kk) = pk;
      }
    }
    // stage B (kq rows, contiguous k)
    #pragma unroll
    for (int i = 0; i < 4; i++) {
      const int c = t + 256 * i;
      const int q = c >> 3, kc = (c & 7) * 8;
      const uint4 v = *(const uint4*)(bbase + (size_t)q * D_ + k0 + kc);
      *(uint4*)(Bs + q * LB + kc) = v;
    }
    __syncthreads();
    #pragma unroll
    for (int ks = 0; ks < 2; ks++) {
      short8 afr[4], bfr[4];
      #pragma unroll
      for (int i = 0; i < 4; i++) {
        const unsigned short* pa = As + (wm + i * 16 + fl) * LA + ks * 32 + fq * 8;
        sv4 lo = *(const sv4*)pa;
        sv4 hi = *(const sv4*)(pa + 4);
        afr[i] = __builtin_shufflevector(lo, hi, 0, 1, 2, 3, 4, 5, 6, 7);
      }
      #pragma unroll
      for (int j = 0; j < 4; j++)
        bfr[j] = *(const short8*)(Bs + (wq + j * 16 + fl) * LB + ks * 32 + fq * 8);
      #pragma unroll
      for (int i = 0; i < 4; i++)
        #pragma unroll
        for (int j = 0; j < 4; j++)
          acc[i][j] = __builtin_amdgcn_mfma_f32_16x16x32_bf16(afr[i], bfr[j], acc[i][j], 0, 0, 0);
    }
  }

  // ---------- softmax with entropy modulation ----------
  const float rsD = 0.03608439182435161f;  // 1/sqrt(768)
  float tev[4], skv[4];
  #pragma unroll
  for (int j = 0; j < 4; j++) {
    int q = wq + j * 16 + fl;
    tev[j] = te[bb * Q_ + q];
    skv[j] = skq[bb * Q_ + q];
  }
  float vev4[4][4];
  #pragma unroll
  for (int i = 0; i < 4; i++)
    #pragma unroll
    for (int r = 0; r < 4; r++)
      vev4[i][r] = ve[(size_t)bb * N_ + n0 + wm + i * 16 + fq * 4 + r];

  float rmax[4][4], rsum[4][4];
  #pragma unroll
  for (int i = 0; i < 4; i++)
    #pragma unroll
    for (int r = 0; r < 4; r++) rmax[i][r] = -__builtin_inff();
  #pragma unroll
  for (int i = 0; i < 4; i++)
    #pragma unroll
    for (int j = 0; j < 4; j++)
      #pragma unroll
      for (int r = 0; r < 4; r++) {
        float L = (acc[i][j][r] + skv[j]) * rsD * vev4[i][r] * tev[j];
        acc[i][j][r] = L;
        rmax[i][r] = fmaxf(rmax[i][r], L);
      }
  #pragma unroll
  for (int off = 1; off < 16; off <<= 1)
    #pragma unroll
    for (int i = 0; i < 4; i++)
      #pragma unroll
      for (int r = 0; r < 4; r++)
        rmax[i][r] = fmaxf(rmax[i][r], __shfl_xor(rmax[i][r], off));
  #pragma unroll
  for (int i = 0; i < 4; i++)
    #pragma unroll
    for (int r = 0; r < 4; r++) rsum[i][r] = 0.f;
  #pragma unroll
  for (int i = 0; i < 4; i++)
    #pragma unroll
    for (int j = 0; j < 4; j++)
      #pragma unroll
      for (int r = 0; r < 4; r++) {
        float e = __expf(acc[i][j][r] - rmax[i][r]);
        acc[i][j][r] = e;
        rsum[i][r] += e;
      }
  #pragma unroll
  for (int off = 1; off < 16; off <<= 1)
    #pragma unroll
    for (int i = 0; i < 4; i++)
      #pragma unroll
      for (int r = 0; r < 4; r++) rsum[i][r] += __shfl_xor(rsum[i][r], off);

  const int qh = wq >> 6;
  if (fl == 0) {
    #pragma unroll
    for (int i = 0; i < 4; i++)
      #pragma unroll
      for (int r = 0; r < 4; r++) {
        int m = wm + i * 16 + fq * 4 + r;
        stats[qh][m][0] = rmax[i][r];
        stats[qh][m][1] = rsum[i][r];
      }
  }
  __syncthreads();  // also ensures ALL waves finished As/Bs reads before Ps overwrite
  float fac[4][4];
  #pragma unroll
  for (int i = 0; i < 4; i++)
    #pragma unroll
    for (int r = 0; r < 4; r++) {
      int m = wm + i * 16 + fq * 4 + r;
      float M2 = stats[1 - qh][m][0], S2 = stats[1 - qh][m][1];
      float Mf = fmaxf(rmax[i][r], M2);
      float sf = rsum[i][r] * __expf(rmax[i][r] - Mf) + S2 * __expf(M2 - Mf);
      fac[i][r] = __expf(rmax[i][r] - Mf) / sf;
    }
  #pragma unroll
  for (int i = 0; i < 4; i++)
    #pragma unroll
    for (int j = 0; j < 4; j++)
      #pragma unroll
      for (int r = 0; r < 4; r++) {
        int m = wm + i * 16 + fq * 4 + r;
        int q = wq + j * 16 + fl;
        Ps[m * LP + q] = f2bf(acc[i][j][r] * fac[i][r]);
      }

  // ---------- phase B: O^T = vT * P^T, d-chunks of 96 ----------
  const int wd = (wave & 1) * 48;   // d half within chunk
  const int wm2 = (wave >> 1) * 64; // token half
  for (int dc = 0; dc < 8; dc++) {
    __syncthreads();  // covers Ps writes (dc=0) and prior-chunk Vs reads
    const unsigned short* vbase = vT + ((size_t)bb * D_ + dc * 96) * Q_;
    #pragma unroll
    for (int i = 0; i < 6; i++) {
      const int c = t + 256 * i;
      const int d = c >> 4, qc = (c & 15) * 8;
      const uint4 v = *(const uint4*)(vbase + (size_t)d * Q_ + qc);
      *(uint4*)(Vs + d * LP + qc) = v;
    }
    __syncthreads();
    f32x4 acc2[3][4];
    #pragma unroll
    for (int i = 0; i < 3; i++)
      #pragma unroll
      for (int j = 0; j < 4; j++) acc2[i][j] = {0.f, 0.f, 0.f, 0.f};
    #pragma unroll
    for (int ks = 0; ks < 4; ks++) {
      short8 vfr[3], pfr[4];
      #pragma unroll
      for (int i = 0; i < 3; i++)
        vfr[i] = *(const short8*)(Vs + (wd + i * 16 + fl) * LP + ks * 32 + fq * 8);
      #pragma unroll
      for (int j = 0; j < 4; j++)
        pfr[j] = *(const short8*)(Ps + (wm2 + j * 16 + fl) * LP + ks * 32 + fq * 8);
      #pragma unroll
      for (int i = 0; i < 3; i++)
        #pragma unroll
        for (int j = 0; j < 4; j++)
          acc2[i][j] = __builtin_amdgcn_mfma_f32_16x16x32_bf16(vfr[i], pfr[j], acc2[i][j], 0, 0, 0);
    }
    float* obase = out + ((size_t)bb * D_ + dc * 96) * N_ + n0;
    #pragma unroll
    for (int i = 0; i < 3; i++)
      #pragma unroll
      for (int j = 0; j < 4; j++) {
        int mm = wm2 + j * 16 + fl;
        #pragma unroll
        for (int r = 0; r < 4; r++) {
          int d = wd + i * 16 + fq * 4 + r;
          obase[(size_t)d * N_ + mm] = acc2[i][j][r];
        }
      }
  }
}

extern "C" void kernel_launch(void* const* d_in, const int* in_sizes, int n_in,
                              void* d_out, int out_size, void* d_ws, size_t ws_size,
                              hipStream_t stream) {
  const float* vis  = (const float*)d_in[0];
  const float* text = (const float*)d_in[1];
  const float* Wq   = (const float*)d_in[2];
  const float* bq   = (const float*)d_in[3];
  const float* Wk   = (const float*)d_in[4];
  const float* bk   = (const float*)d_in[5];
  const float* Wv   = (const float*)d_in[6];
  const float* bv   = (const float*)d_in[7];
  float* out = (float*)d_out;
  char* ws = (char*)d_ws;

  unsigned short* textb = (unsigned short*)(ws + 0);
  unsigned short* WkTb  = (unsigned short*)(ws + 3145728);
  unsigned short* Wvb   = (unsigned short*)(ws + 4325376);
  unsigned short* WqTb  = (unsigned short*)(ws + 5505024);
  unsigned short* W2Tb  = (unsigned short*)(ws + 6684672);
  float* wkbq  = (float*)(ws + 7864320);
  float* bias2 = (float*)(ws + 7867392);
  float* bqbk  = (float*)(ws + 7870464);
  unsigned short* kqb   = (unsigned short*)(ws + 9830400);
  unsigned short* vTb   = (unsigned short*)(ws + 12976128);
  float* ent_t = (float*)(ws + 16121856);
  float* tew   = (float*)(ws + 16130048);
  float* ent_v = (float*)(ws + 16138240);
  float* vew   = (float*)(ws + 16400384);
  float* skq   = (float*)(ws + 16662528);
  unsigned short* visb = (unsigned short*)(ws + 16777216);  // 100,663,296 B
  const bool big = ws_size >= (size_t)16777216 + (size_t)100663296;

  // weight prep + vec-mat folds (independent of text/vis)
  weights_prep_kernel<<<dim3(24, 24, 3), 256, 0, stream>>>(Wv, Wq, Wk, Wvb, WqTb, WkTb);
  vecmat_kernel<<<dim3(3, 3), 256, 0, stream>>>(Wk, Wq, bq, bk, wkbq, bias2, bqbk);
  // text: cast + entropy + skq in one pass
  text_prep_kernel<<<512, 256, 0, stream>>>(text, textb, ent_t, wkbq, bqbk, skq);
  softmax128_kernel<<<16, 128, 0, stream>>>(ent_t, tew);

  // W2T = (Wk^T Wq)^T via NT gemm on the two transposed weights; then kq, vT
  gemm_nt_kernel<0><<<dim3(12, 12), 256, 0, stream>>>(WqTb, WkTb, nullptr, W2Tb);
  gemm_nt_kernel<1><<<dim3(32, 12), 256, 0, stream>>>(textb, W2Tb, bias2, kqb);  // kq = text@W2 + bk@Wq
  gemm_nt_kernel<2><<<dim3(32, 12), 256, 0, stream>>>(textb, Wvb, bv, vTb);      // v^T

  if (big) {
    vis_prep_kernel<<<512, 256, 0, stream>>>(vis, visb, ent_v);
    softmax4096_kernel<<<16, 1024, 0, stream>>>(ent_v, vew);
    attn_main_kernel<1><<<512, 256, 0, stream>>>(vis, visb, kqb, vTb, vew, tew, skq, out);
  } else {
    visual_entropy_kernel<<<1024, 256, 0, stream>>>(vis, ent_v);
    softmax4096_kernel<<<16, 1024, 0, stream>>>(ent_v, vew);
    attn_main_kernel<0><<<512, 256, 0, stream>>>(vis, visb, kqb, vTb, vew, tew, skq, out);
  }
}

// Round 3
// 507.642 us; speedup vs baseline: 1.0779x; 1.0779x over previous
//
#include <hip/hip_runtime.h>

#define B_ 16
#define D_ 768
#define N_ 4096
#define Q_ 128

typedef __attribute__((ext_vector_type(4))) float f32x4;
typedef __attribute__((ext_vector_type(8))) short short8;
typedef __attribute__((ext_vector_type(4))) short sv4;

__device__ __forceinline__ unsigned short f2bf(float f) {
  union { float f; unsigned u; } x; x.f = f;
  unsigned u = x.u;
  unsigned r = u + 0x7fffu + ((u >> 16) & 1u);
  return (unsigned short)(r >> 16);
}

// ---------------- prep: z=0 cast Wv; z=1 transpose Wq; z=2 transpose Wk; ----------------
// z=3: vec-mat folds (by=0: wkbq=Wk^T bq over 3 x-blocks; by=1: bias2=bk^T Wq; by=2,bx=0: bqbk)
__global__ __launch_bounds__(256) void prep_kernel(
    const float* __restrict__ Wv, const float* __restrict__ Wq,
    const float* __restrict__ Wk, const float* __restrict__ bq,
    const float* __restrict__ bk,
    unsigned short* __restrict__ Wvb, unsigned short* __restrict__ WqTb,
    unsigned short* __restrict__ WkTb,
    float* __restrict__ wkbq, float* __restrict__ bias2, float* __restrict__ bqbk) {
  __shared__ float tile[32][33];
  const int z = blockIdx.z;
  const int t = threadIdx.x;
  if (z == 0) {
    int i = (blockIdx.y * 24 + blockIdx.x) * 256 + t;  // 576*256 = 768*768/4
    float4 v = ((const float4*)Wv)[i];
    ushort4 o;
    o.x = f2bf(v.x); o.y = f2bf(v.y); o.z = f2bf(v.z); o.w = f2bf(v.w);
    ((ushort4*)Wvb)[i] = o;
  } else if (z <= 2) {
    const float* src = (z == 1) ? Wq : Wk;
    unsigned short* dst = (z == 1) ? WqTb : WkTb;
    int bx = blockIdx.x * 32, by = blockIdx.y * 32;
    int tx = t & 31, ty = t >> 5;
    #pragma unroll
    for (int i = 0; i < 32; i += 8)
      tile[ty + i][tx] = src[(size_t)(by + ty + i) * D_ + bx + tx];
    __syncthreads();
    #pragma unroll
    for (int i = 0; i < 32; i += 8)
      dst[(size_t)(bx + ty + i) * D_ + by + tx] = f2bf(tile[tx][ty + i]);
  } else {
    const int bx = blockIdx.x, by = blockIdx.y;
    if (by < 2) {
      if (bx >= 3) return;
      const float* M = by ? Wq : Wk;
      const float* vec = by ? bk : bq;
      float* outp = by ? bias2 : wkbq;
      const int col = bx * 256 + t;
      float s = 0.f;
      #pragma unroll 4
      for (int n = 0; n < D_; n++) s += M[(size_t)n * D_ + col] * vec[n];
      outp[col] = s;
    } else if (by == 2 && bx == 0) {
      float s = 0.f;
      for (int k = t; k < D_; k += 256) s += bq[k] * bk[k];
      #pragma unroll
      for (int off = 32; off; off >>= 1) s += __shfl_xor(s, off);
      __shared__ float red[4];
      if ((t & 63) == 0) red[t >> 6] = s;
      __syncthreads();
      if (t == 0) bqbk[0] = red[0] + red[1] + red[2] + red[3];
    }
  }
}

// ---------------- entropy_fused: blocks <1024 visual entropy; >=1024 text prep ----------
__global__ __launch_bounds__(256) void entropy_fused_kernel(
    const float* __restrict__ vis, float* __restrict__ ent_v,
    const float* __restrict__ text, unsigned short* __restrict__ textb,
    float* __restrict__ ent_t, const float* __restrict__ wkbq,
    const float* __restrict__ bqbk, float* __restrict__ skq) {
  __shared__ float ss[256], st[256];
  const int t = threadIdx.x;
  if (blockIdx.x < 1024) {
    // visual: 64 tokens/block, 4 d-slices of 192; no-max online (|v|<~6 -> fp32-safe)
    int bb = blockIdx.x >> 6;
    int n0 = (blockIdx.x & 63) * 64;
    int tok = t & 63, slice = t >> 6;
    const float* base = vis + (size_t)bb * D_ * N_ + (size_t)slice * 192 * N_ + n0 + tok;
    float s = 0.f, tt = 0.f;
    #pragma unroll 4
    for (int d = 0; d < 192; d++) {
      float v = base[(size_t)d * N_];
      float e = __expf(v);
      s += e; tt += v * e;
    }
    ss[t] = s; st[t] = tt;
    __syncthreads();
    if (t < 64) {
      #pragma unroll
      for (int k = 1; k < 4; k++) { s += ss[t + 64 * k]; tt += st[t + 64 * k]; }
      ent_v[(size_t)bb * N_ + n0 + t] = __logf(s) - tt / s;
    }
  } else {
    // text: cast fp32->bf16, row entropy, skq row-dot; one wave per row
    int row = (blockIdx.x - 1024) * 4 + (t >> 6);
    int lane = t & 63;
    const float4* src = (const float4*)(text + (size_t)row * D_);
    const float4* w4p = (const float4*)wkbq;
    ushort4* dst = (ushort4*)(textb + (size_t)row * D_);
    float s = 0.f, tt = 0.f, s2 = 0.f;
    #pragma unroll
    for (int j = 0; j < 3; j++) {
      float4 v = src[lane + 64 * j];
      float4 w = w4p[lane + 64 * j];
      float e0 = __expf(v.x), e1 = __expf(v.y), e2 = __expf(v.z), e3 = __expf(v.w);
      s += (e0 + e1) + (e2 + e3);
      tt += v.x * e0 + v.y * e1;
      tt += v.z * e2 + v.w * e3;
      s2 += v.x * w.x + v.y * w.y + v.z * w.z + v.w * w.w;
      ushort4 o;
      o.x = f2bf(v.x); o.y = f2bf(v.y); o.z = f2bf(v.z); o.w = f2bf(v.w);
      dst[lane + 64 * j] = o;
    }
    #pragma unroll
    for (int off = 32; off; off >>= 1) {
      s += __shfl_xor(s, off);
      tt += __shfl_xor(tt, off);
      s2 += __shfl_xor(s2, off);
    }
    if (lane == 0) {
      ent_t[row] = __logf(s) - tt / s;
      skq[row] = s2 + bqbk[0];
    }
  }
}

// ---------------- softmax_fused: blocks 0..15 softmax4096 -> vew; 16..31 softmax128 -> tew
__global__ __launch_bounds__(1024) void softmax_fused_kernel(
    const float* __restrict__ ent_v, float* __restrict__ vew,
    const float* __restrict__ ent_t, float* __restrict__ tew) {
  __shared__ float red[32];
  __shared__ float sv[128];
  const int b = blockIdx.x, t = threadIdx.x;
  if (b < 16) {
    const float* e = ent_v + (size_t)b * N_;
    float v[4];
    float m = -__builtin_inff();
    #pragma unroll
    for (int i = 0; i < 4; i++) { v[i] = e[t + 1024 * i]; m = fmaxf(m, v[i]); }
    #pragma unroll
    for (int off = 32; off; off >>= 1) m = fmaxf(m, __shfl_xor(m, off));
    int wv = t >> 6;
    if ((t & 63) == 0) red[wv] = m;
    __syncthreads();
    if (t < 16) {
      float x = red[t];
      #pragma unroll
      for (int off = 8; off; off >>= 1) x = fmaxf(x, __shfl_xor(x, off));
      red[t] = x;
    }
    __syncthreads();
    m = red[0];
    float ev[4];
    float s = 0.f;
    #pragma unroll
    for (int i = 0; i < 4; i++) { ev[i] = __expf(v[i] - m); s += ev[i]; }
    #pragma unroll
    for (int off = 32; off; off >>= 1) s += __shfl_xor(s, off);
    __syncthreads();
    if ((t & 63) == 0) red[wv] = s;
    __syncthreads();
    if (t < 16) {
      float x = red[t];
      #pragma unroll
      for (int off = 8; off; off >>= 1) x += __shfl_xor(x, off);
      red[t] = x;
    }
    __syncthreads();
    s = red[0];
    #pragma unroll
    for (int i = 0; i < 4; i++) vew[(size_t)b * N_ + t + 1024 * i] = ev[i] / s;
  } else {
    const int bb = b - 16;
    float v = 0.f;
    if (t < 128) { v = ent_t[bb * 128 + t]; sv[t] = v; }
    __syncthreads();
    if (t < 64) {
      float m = fmaxf(sv[t], sv[t + 64]);
      #pragma unroll
      for (int off = 32; off; off >>= 1) m = fmaxf(m, __shfl_xor(m, off));
      if (t == 0) red[0] = m;
    }
    __syncthreads();
    const float m = red[0];
    float e = 0.f;
    if (t < 128) { e = __expf(v - m); sv[t] = e; }
    __syncthreads();
    if (t < 64) {
      float s = sv[t] + sv[t + 64];
      #pragma unroll
      for (int off = 32; off; off >>= 1) s += __shfl_xor(s, off);
      if (t == 0) red[1] = s;
    }
    __syncthreads();
    if (t < 128) tew[bb * 128 + t] = e / red[1];
  }
}

// ---------------- bf16 NT GEMM (BK=64): C[m,n] = sum_k A[m,k]*B[n,k], bf16 store -------
__global__ __launch_bounds__(256) void gemm_nt_kernel(
    const unsigned short* __restrict__ A, const unsigned short* __restrict__ Bm,
    unsigned short* __restrict__ C) {
  constexpr int LDA = 72;
  __shared__ unsigned short As[64 * LDA];
  __shared__ unsigned short Bs[64 * LDA];
  int m0 = blockIdx.x * 64, n0 = blockIdx.y * 64;
  int t = threadIdx.x, wave = t >> 6, lane = t & 63;
  int wm = (wave & 1) * 32, wn = (wave >> 1) * 32;
  int fl = lane & 15, fq = lane >> 4;
  f32x4 acc[2][2];
  #pragma unroll
  for (int i = 0; i < 2; i++)
    #pragma unroll
    for (int j = 0; j < 2; j++) acc[i][j] = {0.f, 0.f, 0.f, 0.f};
  for (int k0 = 0; k0 < D_; k0 += 64) {
    __syncthreads();
    #pragma unroll
    for (int i = 0; i < 2; i++) {
      int c = t + 256 * i;
      int sr = c >> 3, sc = (c & 7) * 8;
      *(uint4*)(As + sr * LDA + sc) = *(const uint4*)(A + (size_t)(m0 + sr) * D_ + k0 + sc);
      *(uint4*)(Bs + sr * LDA + sc) = *(const uint4*)(Bm + (size_t)(n0 + sr) * D_ + k0 + sc);
    }
    __syncthreads();
    #pragma unroll
    for (int ks = 0; ks < 2; ks++) {
      short8 afr[2], bfr[2];
      #pragma unroll
      for (int i = 0; i < 2; i++)
        afr[i] = *(const short8*)(As + (wm + i * 16 + fl) * LDA + ks * 32 + fq * 8);
      #pragma unroll
      for (int j = 0; j < 2; j++)
        bfr[j] = *(const short8*)(Bs + (wn + j * 16 + fl) * LDA + ks * 32 + fq * 8);
      #pragma unroll
      for (int i = 0; i < 2; i++)
        #pragma unroll
        for (int j = 0; j < 2; j++)
          acc[i][j] = __builtin_amdgcn_mfma_f32_16x16x32_bf16(afr[i], bfr[j], acc[i][j], 0, 0, 0);
    }
  }
  #pragma unroll
  for (int i = 0; i < 2; i++)
    #pragma unroll
    for (int j = 0; j < 2; j++) {
      int n = n0 + wn + j * 16 + fl;
      #pragma unroll
      for (int r = 0; r < 4; r++) {
        int m = m0 + wm + i * 16 + fq * 4 + r;
        C[(size_t)m * D_ + n] = f2bf(acc[i][j][r]);
      }
    }
}

// ---------------- merged kq (+bias2) and vT (+bv, transposed store) GEMM ----------------
// blockIdx.y < 12: kq = text@W2T^T + bias2 -> [2048][768]; else vT[b][n][q] = (text@Wv^T+bv)^T
__global__ __launch_bounds__(256) void gemm_kqvT_kernel(
    const unsigned short* __restrict__ A, const unsigned short* __restrict__ W2T,
    const float* __restrict__ bias2, unsigned short* __restrict__ kqb,
    const unsigned short* __restrict__ Wvb, const float* __restrict__ bv,
    unsigned short* __restrict__ vTb) {
  constexpr int LDA = 72;
  __shared__ unsigned short As[64 * LDA];
  __shared__ unsigned short Bs[64 * LDA];
  const bool isV = blockIdx.y >= 12;
  const unsigned short* Bm = isV ? Wvb : W2T;
  const float* bias = isV ? bv : bias2;
  unsigned short* C = isV ? vTb : kqb;
  int m0 = blockIdx.x * 64, n0 = (isV ? blockIdx.y - 12 : blockIdx.y) * 64;
  int t = threadIdx.x, wave = t >> 6, lane = t & 63;
  int wm = (wave & 1) * 32, wn = (wave >> 1) * 32;
  int fl = lane & 15, fq = lane >> 4;
  f32x4 acc[2][2];
  #pragma unroll
  for (int i = 0; i < 2; i++)
    #pragma unroll
    for (int j = 0; j < 2; j++) acc[i][j] = {0.f, 0.f, 0.f, 0.f};
  for (int k0 = 0; k0 < D_; k0 += 64) {
    __syncthreads();
    #pragma unroll
    for (int i = 0; i < 2; i++) {
      int c = t + 256 * i;
      int sr = c >> 3, sc = (c & 7) * 8;
      *(uint4*)(As + sr * LDA + sc) = *(const uint4*)(A + (size_t)(m0 + sr) * D_ + k0 + sc);
      *(uint4*)(Bs + sr * LDA + sc) = *(const uint4*)(Bm + (size_t)(n0 + sr) * D_ + k0 + sc);
    }
    __syncthreads();
    #pragma unroll
    for (int ks = 0; ks < 2; ks++) {
      short8 afr[2], bfr[2];
      #pragma unroll
      for (int i = 0; i < 2; i++)
        afr[i] = *(const short8*)(As + (wm + i * 16 + fl) * LDA + ks * 32 + fq * 8);
      #pragma unroll
      for (int j = 0; j < 2; j++)
        bfr[j] = *(const short8*)(Bs + (wn + j * 16 + fl) * LDA + ks * 32 + fq * 8);
      #pragma unroll
      for (int i = 0; i < 2; i++)
        #pragma unroll
        for (int j = 0; j < 2; j++)
          acc[i][j] = __builtin_amdgcn_mfma_f32_16x16x32_bf16(afr[i], bfr[j], acc[i][j], 0, 0, 0);
    }
  }
  #pragma unroll
  for (int i = 0; i < 2; i++)
    #pragma unroll
    for (int j = 0; j < 2; j++) {
      int n = n0 + wn + j * 16 + fl;
      float bb = bias[n];
      #pragma unroll
      for (int r = 0; r < 4; r++) {
        int m = m0 + wm + i * 16 + fq * 4 + r;
        float val = acc[i][j][r] + bb;
        if (isV) {
          int bt = m >> 7, q = m & 127;
          C[((size_t)bt * D_ + n) * Q_ + q] = f2bf(val);
        } else {
          C[(size_t)m * D_ + n] = f2bf(val);
        }
      }
    }
}

// ---------------- fused attention main kernel (R0-proven structure) ----------------
// per block: 128 tokens x full Q=128. S = vf*kq^T, softmax w/ ve*te modulation, O^T = vT*P^T
__global__ __launch_bounds__(256, 2) void attn_main_kernel(
    const float* __restrict__ vis,
    const unsigned short* __restrict__ kq,   // [B][Q][768] bf16
    const unsigned short* __restrict__ vT,   // [B][768][Q] bf16
    const float* __restrict__ ve,            // [B][4096]
    const float* __restrict__ te,            // [B][128]
    const float* __restrict__ skq,           // [B*Q]
    float* __restrict__ out)                 // [B][768][4096]
{
  constexpr int LA = 68;   // vf tile stride (bf16): 136B rows -> conflict-free b64 frags
  constexpr int LB = 72;   // kq tile stride: 144B rows -> 16B-aligned b128 frags
  constexpr int LP = 136;  // P and V strides: 272B rows
  __shared__ unsigned short region0[30464];       // 60928 B
  __shared__ float stats[2][128][2];
  unsigned short* As = region0;                   // bytes [0, 17408)
  unsigned short* Bs = region0 + 8704;            // bytes [17408, 35840)
  unsigned short* Ps = region0;                   // bytes [0, 34816)   (A/B dead)
  unsigned short* Vs = region0 + 17408;           // bytes [34816, 60928)

  const int bb = blockIdx.x >> 5;
  const int n0 = (blockIdx.x & 31) * 128;
  const int t = threadIdx.x;
  const int wave = t >> 6, lane = t & 63;
  const int fl = lane & 15, fq = lane >> 4;
  const int wm = (wave & 1) * 64;   // token half (phase A)
  const int wq = (wave >> 1) * 64;  // q half (phase A)

  const float* abase = vis + (size_t)bb * D_ * N_ + n0;
  const unsigned short* bbase = kq + (size_t)bb * Q_ * D_;

  f32x4 acc[4][4];
  #pragma unroll
  for (int i = 0; i < 4; i++)
    #pragma unroll
    for (int j = 0; j < 4; j++) acc[i][j] = {0.f, 0.f, 0.f, 0.f};

  const int smi = t & 127;
  const int ph = t >> 7;

  // ---------- phase A: S = vf * kq^T ----------
  for (int k0 = 0; k0 < D_; k0 += 64) {
    __syncthreads();
    // stage A (transpose fp32 [k][n] -> bf16 [m][k]), paired writes
    #pragma unroll
    for (int i = 0; i < 16; i++) {
      const int kk = 2 * (ph + 2 * i);
      const float v0 = abase[(size_t)(k0 + kk) * N_ + smi];
      const float v1 = abase[(size_t)(k0 + kk + 1) * N_ + smi];
      const unsigned pk = (unsigned)f2bf(v0) | ((unsigned)f2bf(v1) << 16);
      *(unsigned*)(As + smi * LA + kk) = pk;
    }
    // stage B (kq rows, contiguous k)
    #pragma unroll
    for (int i = 0; i < 4; i++) {
      const int c = t + 256 * i;
      const int q = c >> 3, kc = (c & 7) * 8;
      const uint4 v = *(const uint4*)(bbase + (size_t)q * D_ + k0 + kc);
      *(uint4*)(Bs + q * LB + kc) = v;
    }
    __syncthreads();
    #pragma unroll
    for (int ks = 0; ks < 2; ks++) {
      short8 afr[4], bfr[4];
      #pragma unroll
      for (int i = 0; i < 4; i++) {
        const unsigned short* pa = As + (wm + i * 16 + fl) * LA + ks * 32 + fq * 8;
        sv4 lo = *(const sv4*)pa;
        sv4 hi = *(const sv4*)(pa + 4);
        afr[i] = __builtin_shufflevector(lo, hi, 0, 1, 2, 3, 4, 5, 6, 7);
      }
      #pragma unroll
      for (int j = 0; j < 4; j++)
        bfr[j] = *(const short8*)(Bs + (wq + j * 16 + fl) * LB + ks * 32 + fq * 8);
      #pragma unroll
      for (int i = 0; i < 4; i++)
        #pragma unroll
        for (int j = 0; j < 4; j++)
          acc[i][j] = __builtin_amdgcn_mfma_f32_16x16x32_bf16(afr[i], bfr[j], acc[i][j], 0, 0, 0);
    }
  }

  // ---------- softmax with entropy modulation ----------
  const float rsD = 0.03608439182435161f;  // 1/sqrt(768)
  float tev[4], skv[4];
  #pragma unroll
  for (int j = 0; j < 4; j++) {
    int q = wq + j * 16 + fl;
    tev[j] = te[bb * Q_ + q];
    skv[j] = skq[bb * Q_ + q];
  }
  float vev4[4][4];
  #pragma unroll
  for (int i = 0; i < 4; i++)
    #pragma unroll
    for (int r = 0; r < 4; r++)
      vev4[i][r] = ve[(size_t)bb * N_ + n0 + wm + i * 16 + fq * 4 + r];

  float rmax[4][4], rsum[4][4];
  #pragma unroll
  for (int i = 0; i < 4; i++)
    #pragma unroll
    for (int r = 0; r < 4; r++) rmax[i][r] = -__builtin_inff();
  #pragma unroll
  for (int i = 0; i < 4; i++)
    #pragma unroll
    for (int j = 0; j < 4; j++)
      #pragma unroll
      for (int r = 0; r < 4; r++) {
        float L = (acc[i][j][r] + skv[j]) * rsD * vev4[i][r] * tev[j];
        acc[i][j][r] = L;
        rmax[i][r] = fmaxf(rmax[i][r], L);
      }
  #pragma unroll
  for (int off = 1; off < 16; off <<= 1)
    #pragma unroll
    for (int i = 0; i < 4; i++)
      #pragma unroll
      for (int r = 0; r < 4; r++)
        rmax[i][r] = fmaxf(rmax[i][r], __shfl_xor(rmax[i][r], off));
  #pragma unroll
  for (int i = 0; i < 4; i++)
    #pragma unroll
    for (int r = 0; r < 4; r++) rsum[i][r] = 0.f;
  #pragma unroll
  for (int i = 0; i < 4; i++)
    #pragma unroll
    for (int j = 0; j < 4; j++)
      #pragma unroll
      for (int r = 0; r < 4; r++) {
        float e = __expf(acc[i][j][r] - rmax[i][r]);
        acc[i][j][r] = e;
        rsum[i][r] += e;
      }
  #pragma unroll
  for (int off = 1; off < 16; off <<= 1)
    #pragma unroll
    for (int i = 0; i < 4; i++)
      #pragma unroll
      for (int r = 0; r < 4; r++) rsum[i][r] += __shfl_xor(rsum[i][r], off);

  const int qh = wq >> 6;
  if (fl == 0) {
    #pragma unroll
    for (int i = 0; i < 4; i++)
      #pragma unroll
      for (int r = 0; r < 4; r++) {
        int m = wm + i * 16 + fq * 4 + r;
        stats[qh][m][0] = rmax[i][r];
        stats[qh][m][1] = rsum[i][r];
      }
  }
  __syncthreads();  // also ensures ALL waves finished As/Bs reads before Ps overwrite
  float fac[4][4];
  #pragma unroll
  for (int i = 0; i < 4; i++)
    #pragma unroll
    for (int r = 0; r < 4; r++) {
      int m = wm + i * 16 + fq * 4 + r;
      float M2 = stats[1 - qh][m][0], S2 = stats[1 - qh][m][1];
      float Mf = fmaxf(rmax[i][r], M2);
      float sf = rsum[i][r] * __expf(rmax[i][r] - Mf) + S2 * __expf(M2 - Mf);
      fac[i][r] = __expf(rmax[i][r] - Mf) / sf;
    }
  #pragma unroll
  for (int i = 0; i < 4; i++)
    #pragma unroll
    for (int j = 0; j < 4; j++)
      #pragma unroll
      for (int r = 0; r < 4; r++) {
        int m = wm + i * 16 + fq * 4 + r;
        int q = wq + j * 16 + fl;
        Ps[m * LP + q] = f2bf(acc[i][j][r] * fac[i][r]);
      }

  // ---------- phase B: O^T = vT * P^T, d-chunks of 96 ----------
  const int wd = (wave & 1) * 48;   // d half within chunk
  const int wm2 = (wave >> 1) * 64; // token half
  for (int dc = 0; dc < 8; dc++) {
    __syncthreads();  // covers Ps writes (dc=0) and prior-chunk Vs reads
    const unsigned short* vbase = vT + ((size_t)bb * D_ + dc * 96) * Q_;
    #pragma unroll
    for (int i = 0; i < 6; i++) {
      const int c = t + 256 * i;
      const int d = c >> 4, qc = (c & 15) * 8;
      const uint4 v = *(const uint4*)(vbase + (size_t)d * Q_ + qc);
      *(uint4*)(Vs + d * LP + qc) = v;
    }
    __syncthreads();
    f32x4 acc2[3][4];
    #pragma unroll
    for (int i = 0; i < 3; i++)
      #pragma unroll
      for (int j = 0; j < 4; j++) acc2[i][j] = {0.f, 0.f, 0.f, 0.f};
    #pragma unroll
    for (int ks = 0; ks < 4; ks++) {
      short8 vfr[3], pfr[4];
      #pragma unroll
      for (int i = 0; i < 3; i++)
        vfr[i] = *(const short8*)(Vs + (wd + i * 16 + fl) * LP + ks * 32 + fq * 8);
      #pragma unroll
      for (int j = 0; j < 4; j++)
        pfr[j] = *(const short8*)(Ps + (wm2 + j * 16 + fl) * LP + ks * 32 + fq * 8);
      #pragma unroll
      for (int i = 0; i < 3; i++)
        #pragma unroll
        for (int j = 0; j < 4; j++)
          acc2[i][j] = __builtin_amdgcn_mfma_f32_16x16x32_bf16(vfr[i], pfr[j], acc2[i][j], 0, 0, 0);
    }
    float* obase = out + ((size_t)bb * D_ + dc * 96) * N_ + n0;
    #pragma unroll
    for (int i = 0; i < 3; i++)
      #pragma unroll
      for (int j = 0; j < 4; j++) {
        int mm = wm2 + j * 16 + fl;
        #pragma unroll
        for (int r = 0; r < 4; r++) {
          int d = wd + i * 16 + fq * 4 + r;
          obase[(size_t)d * N_ + mm] = acc2[i][j][r];
        }
      }
  }
}

extern "C" void kernel_launch(void* const* d_in, const int* in_sizes, int n_in,
                              void* d_out, int out_size, void* d_ws, size_t ws_size,
                              hipStream_t stream) {
  const float* vis  = (const float*)d_in[0];
  const float* text = (const float*)d_in[1];
  const float* Wq   = (const float*)d_in[2];
  const float* bq   = (const float*)d_in[3];
  const float* Wk   = (const float*)d_in[4];
  const float* bk   = (const float*)d_in[5];
  const float* Wv   = (const float*)d_in[6];
  const float* bv   = (const float*)d_in[7];
  float* out = (float*)d_out;
  char* ws = (char*)d_ws;

  unsigned short* textb = (unsigned short*)(ws + 0);
  unsigned short* WkTb  = (unsigned short*)(ws + 3145728);
  unsigned short* Wvb   = (unsigned short*)(ws + 4325376);
  unsigned short* WqTb  = (unsigned short*)(ws + 5505024);
  unsigned short* W2Tb  = (unsigned short*)(ws + 6684672);
  float* wkbq  = (float*)(ws + 7864320);
  float* bias2 = (float*)(ws + 7867392);
  float* bqbk  = (float*)(ws + 7870464);
  unsigned short* kqb   = (unsigned short*)(ws + 9830400);
  unsigned short* vTb   = (unsigned short*)(ws + 12976128);
  float* ent_t = (float*)(ws + 16121856);
  float* tew   = (float*)(ws + 16130048);
  float* ent_v = (float*)(ws + 16138240);
  float* vew   = (float*)(ws + 16400384);
  float* skq   = (float*)(ws + 16662528);
  // total ws: 16,670,720 bytes

  // 1. weight casts/transposes + vec-mat folds
  prep_kernel<<<dim3(24, 24, 4), 256, 0, stream>>>(Wv, Wq, Wk, bq, bk,
                                                   Wvb, WqTb, WkTb, wkbq, bias2, bqbk);
  // 2. visual entropy || text cast+entropy+skq
  entropy_fused_kernel<<<1536, 256, 0, stream>>>(vis, ent_v, text, textb, ent_t,
                                                 wkbq, bqbk, skq);
  // 3. softmax4096 (ve) || softmax128 (te)
  softmax_fused_kernel<<<32, 1024, 0, stream>>>(ent_v, vew, ent_t, tew);
  // 4. W2T = (Wk^T Wq)^T
  gemm_nt_kernel<<<dim3(12, 12), 256, 0, stream>>>(WqTb, WkTb, W2Tb);
  // 5. kq = text@W2 + bias2 || vT
  gemm_kqvT_kernel<<<dim3(32, 24), 256, 0, stream>>>(textb, W2Tb, bias2, kqb, Wvb, bv, vTb);
  // 6. fused attention
  attn_main_kernel<<<512, 256, 0, stream>>>(vis, kqb, vTb, vew, tew, skq, out);
}